// Round 7
// baseline (415.369 us; speedup 1.0000x reference)
//
#include <hip/hip_runtime.h>

// Problem constants: V=27, E=64, H=128, B=256, S=512 (enc and dec)
#define V_ 27
#define E_ 64
#define H_ 128
#define S_ 512

typedef float f32x4 __attribute__((ext_vector_type(4)));

// Barrier WITHOUT vmcnt drain: LDS visibility only. Global loads/stores stay in flight.
#define BAR() asm volatile("s_waitcnt lgkmcnt(0)\n\ts_barrier" ::: "memory")

// Pin a value into VGPRs: prevents scratch demotion / load rematerialization.
#define PIN(X) asm volatile("" : "+v"(X))

// Hazard-safe DPP add (compiler inserts required wait states; raw asm DPP does not).
template<int CTRL>
__device__ __forceinline__ float dpp_add(float x) {
    int y = __builtin_amdgcn_update_dpp(0, __builtin_bit_cast(int, x), CTRL, 0xF, 0xF, true);
    return x + __builtin_bit_cast(float, y);
}
#define QP_1032 0xB1   // quad_perm [1,0,3,2]
#define QP_2301 0x4E   // quad_perm [2,3,0,1]
#define RR8 0x128      // row_ror:8
#define RR4 0x124      // row_ror:4
#define RR2 0x122      // row_ror:2
#define RR1 0x121      // row_ror:1

// tanh(z) = 1 - 2/(e^{2z}+1); fp32-stable at both extremes.
__device__ __forceinline__ float fast_tanhf(float z) {
    float e = __expf(2.0f * z);
    return 1.0f - __fdividef(2.0f, e + 1.0f);
}

__device__ __forceinline__ float dot8(f32x4 a, f32x4 b, f32x4 wa, f32x4 wb) {
    float p = a.x * wa.x;
    p = fmaf(a.y, wa.y, p); p = fmaf(a.z, wa.z, p); p = fmaf(a.w, wa.w, p);
    p = fmaf(b.x, wb.x, p); p = fmaf(b.y, wb.y, p); p = fmaf(b.z, wb.z, p);
    p = fmaf(b.w, wb.w, p);
    return p;
}

// ---------- prep kernel: T[tbl][v][j] = b[j] + sum_e embed[v][e]*Wx[e][j] ----------
__global__ void prep_T(const float* __restrict__ embed,
                       const float* __restrict__ eWx, const float* __restrict__ eb,
                       const float* __restrict__ dWx, const float* __restrict__ db_,
                       float* __restrict__ Tg) {
    int tbl = blockIdx.x / V_;
    int v   = blockIdx.x - tbl * V_;
    int j   = threadIdx.x;
    const float* Wx = tbl ? dWx : eWx;
    const float* bb = tbl ? db_ : eb;
    float s = bb[j];
    #pragma unroll
    for (int e = 0; e < E_; ++e) s = fmaf(embed[v * E_ + e], Wx[e * H_ + j], s);
    Tg[tbl * V_ * H_ + v * H_ + j] = s;
}

// Weight registers Ri = Wh[(8kk+i)*H + j0 .. j0+3]; p_m accumulates hv_i * Ri[m].
#define ACC4(HV, R) \
    p0 = fmaf((HV), (R).x, p0); p1 = fmaf((HV), (R).y, p1); \
    p2 = fmaf((HV), (R).z, p2); p3 = fmaf((HV), (R).w, p3)

// One RNN step. DENSEF/LOADPAIRF are literal true/false (dead code eliminated).
#define RNN_STEP(HSRC, HDST, DENSEF, LOADPAIRF, IDP, TGB, DOSTORE, OUTP) do {       \
    int2 idpr_n = idpr;                                                             \
    if (LOADPAIRF) idpr_n = *(const int2*)((IDP) + 2);   /* ids[t+2..t+3], b64 */   \
    float Tv_n = (TGB)[id_next * H_ + jdiag];            /* global prefetch t+1 */  \
    const f32x4* hbp = (const f32x4*)((HSRC) + 12 * kk);                            \
    f32x4 ha = hbp[0], hc = hbp[1];                      /* 2x ds_read_b128 */      \
    float p0 = 0.f, p1 = 0.f, p2 = 0.f, p3 = 0.f;                                   \
    ACC4(ha.x, R0); ACC4(ha.y, R1); ACC4(ha.z, R2); ACC4(ha.w, R3);                 \
    ACC4(hc.x, R4); ACC4(hc.y, R5); ACC4(hc.z, R6); ACC4(hc.w, R7);                 \
    p0 = dpp_add<QP_2301>(dpp_add<QP_1032>(p0));                                    \
    p1 = dpp_add<QP_2301>(dpp_add<QP_1032>(p1));                                    \
    p2 = dpp_add<QP_2301>(dpp_add<QP_1032>(p2));                                    \
    p3 = dpp_add<QP_2301>(dpp_add<QP_1032>(p3));                                    \
    float s01 = c1 ? p1 : p0;                                                       \
    float s23 = c1 ? p3 : p2;                                                       \
    float r   = c2 ? s23 : s01;                                                     \
    r = dpp_add<RR8>(r);                                                            \
    r = dpp_add<RR4>(r);                                                            \
    float hnew = fast_tanhf(r + Tv);                                                \
    if (wrlane) (HDST)[wrword] = hnew;                   /* b32, 16 lanes/wave */   \
    if (DENSEF) {                                                                   \
        float d = dot8(ha, hc, D0, D1);                                             \
        d = dpp_add<RR1>(dpp_add<RR2>(dpp_add<RR4>(dpp_add<RR8>(d))));              \
        if (DOSTORE) (OUTP)[0] = d + db;                 /* vmcnt never drained */  \
    }                                                                               \
    BAR();                                                                          \
    if (LOADPAIRF) { idpr = idpr_n; id_next = idpr_n.x; }                           \
    else           { id_next = idpr.y; }                                            \
    Tv = Tv_n;                                                                      \
} while (0)

__global__ __launch_bounds__(512, 1)
void seq2seq_rnn_kernel(const int* __restrict__ enc_ids, const int* __restrict__ dec_ids,
                        const float* __restrict__ enc_Wh, const float* __restrict__ dec_Wh,
                        const float* __restrict__ dense_W, const float* __restrict__ dense_b,
                        const float* __restrict__ Tg,      // [2][27][128] in d_ws
                        float* __restrict__ out) {
    __shared__ __align__(16) float lds_h0[192];   // 16 groups of 8, stride 12
    __shared__ __align__(16) float lds_h1[192];
    __shared__ __align__(16) int   lds_ids[2 * S_ + 2];

    const int tid  = threadIdx.x;
    const int b    = blockIdx.x;
    const int lane = tid & 63;
    const int w    = tid >> 6;
    const int jl   = lane >> 4;
    const int kk   = lane & 15;
    const int j0     = (w << 4) + (jl << 2);
    const int jdiag  = j0 + (lane & 3);
    const int wrword = 12 * (jdiag >> 3) + (jdiag & 7);
    const bool wrlane = (kk < 4);
    const bool c1 = (lane & 1) != 0;
    const bool c2 = (lane & 2) != 0;
    const int vd   = (w << 2) | jl;               // dense logit slot (27 of 32 used)

    // ---- stage ids; zero h0 ----
    if (tid < 256) ((int2*)lds_ids)[tid] = ((const int2*)(enc_ids + b * S_))[tid];
    else ((int2*)(lds_ids + S_))[tid - 256] = ((const int2*)(dec_ids + b * S_))[tid - 256];
    if (tid < 2) lds_ids[2 * S_ + tid] = 0;
    if (tid < 192) lds_h0[tid] = 0.0f;

    // ---- recurrent weights in NAMED vector registers (no arrays -> no scratch) ----
    // Ri = Wh[(8kk+i)*H + j0 .. j0+3], loaded as b128.
    f32x4 R0, R1, R2, R3, R4, R5, R6, R7;
    {
        const float* wp = enc_Wh + (8 * kk) * H_ + j0;
        R0 = *(const f32x4*)(wp + 0 * H_); R1 = *(const f32x4*)(wp + 1 * H_);
        R2 = *(const f32x4*)(wp + 2 * H_); R3 = *(const f32x4*)(wp + 3 * H_);
        R4 = *(const f32x4*)(wp + 4 * H_); R5 = *(const f32x4*)(wp + 5 * H_);
        R6 = *(const f32x4*)(wp + 6 * H_); R7 = *(const f32x4*)(wp + 7 * H_);
    }
    PIN(R0); PIN(R1); PIN(R2); PIN(R3); PIN(R4); PIN(R5); PIN(R6); PIN(R7);

    // ---- dense weights: D{0,1}[i] = dense_W[(8kk+i)*V + vd] ----
    f32x4 D0, D1; float db = 0.0f;
    {
        int vc = (vd < V_) ? vd : 0;
        const float* dp = dense_W + (8 * kk) * V_ + vc;
        D0.x = dp[0 * V_]; D0.y = dp[1 * V_]; D0.z = dp[2 * V_]; D0.w = dp[3 * V_];
        D1.x = dp[4 * V_]; D1.y = dp[5 * V_]; D1.z = dp[6 * V_]; D1.w = dp[7 * V_];
        if (vd < V_) db = dense_b[vd];
    }
    PIN(D0); PIN(D1);
    const bool dlane = (kk == 0) && (vd < V_);
    float* outd = out + b * (S_ * V_) + vd;
    __syncthreads();   // ids + h0 ready

    // ================= encoder: 512 steps =================
    {
        int2  idpr = make_int2(0, 0);
        int   id_next = lds_ids[1];
        float Tv      = Tg[lds_ids[0] * H_ + jdiag];
        for (int t = 0; t < S_; t += 2) {
            RNN_STEP(lds_h0, lds_h1, false, true,  lds_ids + t, Tg, false, (float*)out);
            RNN_STEP(lds_h1, lds_h0, false, false, lds_ids + t, Tg, false, (float*)out);
        }
    }

    // ---- swap to decoder recurrent weights ----
    {
        const float* wp = dec_Wh + (8 * kk) * H_ + j0;
        R0 = *(const f32x4*)(wp + 0 * H_); R1 = *(const f32x4*)(wp + 1 * H_);
        R2 = *(const f32x4*)(wp + 2 * H_); R3 = *(const f32x4*)(wp + 3 * H_);
        R4 = *(const f32x4*)(wp + 4 * H_); R5 = *(const f32x4*)(wp + 5 * H_);
        R6 = *(const f32x4*)(wp + 6 * H_); R7 = *(const f32x4*)(wp + 7 * H_);
    }
    PIN(R0); PIN(R1); PIN(R2); PIN(R3); PIN(R4); PIN(R5); PIN(R6); PIN(R7);

    // ================= decoder: 512 steps; dense piggybacked =================
    // Step t reads buffer holding dec state after step t-1 -> dense -> out[(t-1)*V].
    {
        const int*   ids_d = lds_ids + S_;
        const float* Td    = Tg + V_ * H_;
        int2  idpr = make_int2(0, 0);
        int   id_next = ids_d[1];
        float Tv      = Td[ids_d[0] * H_ + jdiag];
        for (int t = 0; t < S_; t += 2) {
            RNN_STEP(lds_h0, lds_h1, true, true,  ids_d + t, Td,
                     dlane && (t > 0), outd + (t - 1) * V_);
            RNN_STEP(lds_h1, lds_h0, true, false, ids_d + t, Td,
                     dlane, outd + t * V_);
        }
    }

    // epilogue: dense on final state (decoder t=511 wrote lds_h0) -> logits[511]
    {
        const f32x4* hbp = (const f32x4*)(lds_h0 + 12 * kk);
        f32x4 ha = hbp[0], hc = hbp[1];
        float d = dot8(ha, hc, D0, D1);
        d = dpp_add<RR1>(dpp_add<RR2>(dpp_add<RR4>(dpp_add<RR8>(d))));
        if (dlane) outd[(S_ - 1) * V_] = d + db;
    }
}

extern "C" void kernel_launch(void* const* d_in, const int* in_sizes, int n_in,
                              void* d_out, int out_size, void* d_ws, size_t ws_size,
                              hipStream_t stream) {
    const int*   enc_ids = (const int*)d_in[0];
    const int*   dec_ids = (const int*)d_in[1];
    const float* embed   = (const float*)d_in[2];
    const float* enc_Wx  = (const float*)d_in[3];
    const float* enc_Wh  = (const float*)d_in[4];
    const float* enc_b   = (const float*)d_in[5];
    const float* dec_Wx  = (const float*)d_in[6];
    const float* dec_Wh  = (const float*)d_in[7];
    const float* dec_b   = (const float*)d_in[8];
    const float* dense_W = (const float*)d_in[9];
    const float* dense_b = (const float*)d_in[10];
    float* out = (float*)d_out;
    float* Tg  = (float*)d_ws;   // 2*27*128 floats = 27648 B

    hipLaunchKernelGGL(prep_T, dim3(2 * V_), dim3(H_), 0, stream,
                       embed, enc_Wx, enc_b, dec_Wx, dec_b, Tg);
    hipLaunchKernelGGL(seq2seq_rnn_kernel, dim3(256), dim3(512), 0, stream,
                       enc_ids, dec_ids, enc_Wh, dec_Wh, dense_W, dense_b, Tg, out);
}

// Round 8
// 410.637 us; speedup vs baseline: 1.0115x; 1.0115x over previous
//
#include <hip/hip_runtime.h>

// Problem constants: V=27, E=64, H=128, B=256, S=512 (enc and dec)
#define V_ 27
#define E_ 64
#define H_ 128
#define S_ 512

typedef float f32x4 __attribute__((ext_vector_type(4)));

// Barrier WITHOUT vmcnt drain: LDS visibility only. Global loads/stores stay in flight.
#define BAR() asm volatile("s_waitcnt lgkmcnt(0)\n\ts_barrier" ::: "memory")

// Per-iteration register pins: force weight residency (defeat load remat/sinking).
#define PINW() asm volatile("" : "+v"(R0), "+v"(R1), "+v"(R2), "+v"(R3), \
                                 "+v"(R4), "+v"(R5), "+v"(R6), "+v"(R7))
#define PIND() asm volatile("" : "+v"(D0), "+v"(D1))

// Hazard-safe DPP add (compiler inserts required wait states; raw asm DPP does not).
template<int CTRL>
__device__ __forceinline__ float dpp_add(float x) {
    int y = __builtin_amdgcn_update_dpp(0, __builtin_bit_cast(int, x), CTRL, 0xF, 0xF, true);
    return x + __builtin_bit_cast(float, y);
}
#define QP_1032 0xB1   // quad_perm [1,0,3,2]
#define QP_2301 0x4E   // quad_perm [2,3,0,1]
#define RR8 0x128      // row_ror:8
#define RR4 0x124      // row_ror:4
#define RR2 0x122      // row_ror:2
#define RR1 0x121      // row_ror:1

// tanh(z) = 1 - 2/(e^{2z}+1); fp32-stable at both extremes.
__device__ __forceinline__ float fast_tanhf(float z) {
    float e = __expf(2.0f * z);
    return 1.0f - __fdividef(2.0f, e + 1.0f);
}

__device__ __forceinline__ float dot8(f32x4 a, f32x4 b, f32x4 wa, f32x4 wb) {
    float p = a.x * wa.x;
    p = fmaf(a.y, wa.y, p); p = fmaf(a.z, wa.z, p); p = fmaf(a.w, wa.w, p);
    p = fmaf(b.x, wb.x, p); p = fmaf(b.y, wb.y, p); p = fmaf(b.z, wb.z, p);
    p = fmaf(b.w, wb.w, p);
    return p;
}

// ---------- prep kernel: T[tbl][v][j] = b[j] + sum_e embed[v][e]*Wx[e][j] ----------
__global__ void prep_T(const float* __restrict__ embed,
                       const float* __restrict__ eWx, const float* __restrict__ eb,
                       const float* __restrict__ dWx, const float* __restrict__ db_,
                       float* __restrict__ Tg) {
    int tbl = blockIdx.x / V_;
    int v   = blockIdx.x - tbl * V_;
    int j   = threadIdx.x;
    const float* Wx = tbl ? dWx : eWx;
    const float* bb = tbl ? db_ : eb;
    float s = bb[j];
    #pragma unroll
    for (int e = 0; e < E_; ++e) s = fmaf(embed[v * E_ + e], Wx[e * H_ + j], s);
    Tg[tbl * V_ * H_ + v * H_ + j] = s;
}

// Weight registers Ri = Wh[(8kk+i)*H + j0 .. j0+3]; p_m accumulates hv_i * Ri[m].
#define ACC4(HV, R) \
    p0 = fmaf((HV), (R).x, p0); p1 = fmaf((HV), (R).y, p1); \
    p2 = fmaf((HV), (R).z, p2); p3 = fmaf((HV), (R).w, p3)

// One RNN step. DENSEF/LOADPAIRF are literal true/false (dead code eliminated).
#define RNN_STEP(HSRC, HDST, DENSEF, LOADPAIRF, IDP, TGB, DOSTORE, OUTP) do {       \
    PINW();                                                                         \
    if (DENSEF) PIND();                                                             \
    int2 idpr_n = idpr;                                                             \
    if (LOADPAIRF) idpr_n = *(const int2*)((IDP) + 2);   /* ids[t+2..t+3], b64 */   \
    float Tv_n = (TGB)[id_next * H_ + jdiag];            /* global prefetch t+1 */  \
    const f32x4* hbp = (const f32x4*)((HSRC) + 12 * kk);                            \
    f32x4 ha = hbp[0], hc = hbp[1];                      /* 2x ds_read_b128 */      \
    float p0 = 0.f, p1 = 0.f, p2 = 0.f, p3 = 0.f;                                   \
    ACC4(ha.x, R0); ACC4(ha.y, R1); ACC4(ha.z, R2); ACC4(ha.w, R3);                 \
    ACC4(hc.x, R4); ACC4(hc.y, R5); ACC4(hc.z, R6); ACC4(hc.w, R7);                 \
    p0 = dpp_add<QP_2301>(dpp_add<QP_1032>(p0));                                    \
    p1 = dpp_add<QP_2301>(dpp_add<QP_1032>(p1));                                    \
    p2 = dpp_add<QP_2301>(dpp_add<QP_1032>(p2));                                    \
    p3 = dpp_add<QP_2301>(dpp_add<QP_1032>(p3));                                    \
    float s01 = c1 ? p1 : p0;                                                       \
    float s23 = c1 ? p3 : p2;                                                       \
    float r   = c2 ? s23 : s01;                                                     \
    r = dpp_add<RR8>(r);                                                            \
    r = dpp_add<RR4>(r);                                                            \
    float hnew = fast_tanhf(r + Tv);                                                \
    if (wrlane) (HDST)[wrword] = hnew;                   /* b32, 16 lanes/wave */   \
    if (DENSEF) {                                                                   \
        float d = dot8(ha, hc, D0, D1);                                             \
        d = dpp_add<RR1>(dpp_add<RR2>(dpp_add<RR4>(dpp_add<RR8>(d))));              \
        if (DOSTORE) (OUTP)[0] = d + db;                 /* vmcnt never drained */  \
    }                                                                               \
    BAR();                                                                          \
    if (LOADPAIRF) { idpr = idpr_n; id_next = idpr_n.x; }                           \
    else           { id_next = idpr.y; }                                            \
    Tv = Tv_n;                                                                      \
} while (0)

__global__ __attribute__((amdgpu_flat_work_group_size(512, 512), amdgpu_waves_per_eu(2, 2)))
void seq2seq_rnn_kernel(const int* __restrict__ enc_ids, const int* __restrict__ dec_ids,
                        const float* __restrict__ enc_Wh, const float* __restrict__ dec_Wh,
                        const float* __restrict__ dense_W, const float* __restrict__ dense_b,
                        const float* __restrict__ Tg,      // [2][27][128] in d_ws
                        float* __restrict__ out) {
    __shared__ __align__(16) float lds_h0[192];   // 16 groups of 8, stride 12
    __shared__ __align__(16) float lds_h1[192];
    __shared__ __align__(16) int   lds_ids[2 * S_ + 2];

    const int tid  = threadIdx.x;
    const int b    = blockIdx.x;
    const int lane = tid & 63;
    const int w    = tid >> 6;
    const int jl   = lane >> 4;
    const int kk   = lane & 15;
    const int j0     = (w << 4) + (jl << 2);
    const int jdiag  = j0 + (lane & 3);
    const int wrword = 12 * (jdiag >> 3) + (jdiag & 7);
    const bool wrlane = (kk < 4);
    const bool c1 = (lane & 1) != 0;
    const bool c2 = (lane & 2) != 0;
    const int vd   = (w << 2) | jl;               // dense logit slot (27 of 32 used)

    // ---- stage ids; zero h0 ----
    if (tid < 256) ((int2*)lds_ids)[tid] = ((const int2*)(enc_ids + b * S_))[tid];
    else ((int2*)(lds_ids + S_))[tid - 256] = ((const int2*)(dec_ids + b * S_))[tid - 256];
    if (tid < 2) lds_ids[2 * S_ + tid] = 0;
    if (tid < 192) lds_h0[tid] = 0.0f;

    // ---- recurrent weights in NAMED vector registers ----
    // Ri = Wh[(8kk+i)*H + j0 .. j0+3], loaded as b128.
    f32x4 R0, R1, R2, R3, R4, R5, R6, R7;
    {
        const float* wp = enc_Wh + (8 * kk) * H_ + j0;
        R0 = *(const f32x4*)(wp + 0 * H_); R1 = *(const f32x4*)(wp + 1 * H_);
        R2 = *(const f32x4*)(wp + 2 * H_); R3 = *(const f32x4*)(wp + 3 * H_);
        R4 = *(const f32x4*)(wp + 4 * H_); R5 = *(const f32x4*)(wp + 5 * H_);
        R6 = *(const f32x4*)(wp + 6 * H_); R7 = *(const f32x4*)(wp + 7 * H_);
    }

    // ---- dense weights: D{0,1}[i] = dense_W[(8kk+i)*V + vd] ----
    f32x4 D0, D1; float db = 0.0f;
    {
        int vc = (vd < V_) ? vd : 0;
        const float* dp = dense_W + (8 * kk) * V_ + vc;
        D0.x = dp[0 * V_]; D0.y = dp[1 * V_]; D0.z = dp[2 * V_]; D0.w = dp[3 * V_];
        D1.x = dp[4 * V_]; D1.y = dp[5 * V_]; D1.z = dp[6 * V_]; D1.w = dp[7 * V_];
        if (vd < V_) db = dense_b[vd];
    }
    const bool dlane = (kk == 0) && (vd < V_);
    float* outd = out + b * (S_ * V_) + vd;
    __syncthreads();   // ids + h0 ready

    // ================= encoder: 512 steps =================
    {
        int2  idpr = make_int2(0, 0);
        int   id_next = lds_ids[1];
        float Tv      = Tg[lds_ids[0] * H_ + jdiag];
        for (int t = 0; t < S_; t += 2) {
            RNN_STEP(lds_h0, lds_h1, false, true,  lds_ids + t, Tg, false, (float*)out);
            RNN_STEP(lds_h1, lds_h0, false, false, lds_ids + t, Tg, false, (float*)out);
        }
    }

    // ---- swap to decoder recurrent weights ----
    {
        const float* wp = dec_Wh + (8 * kk) * H_ + j0;
        R0 = *(const f32x4*)(wp + 0 * H_); R1 = *(const f32x4*)(wp + 1 * H_);
        R2 = *(const f32x4*)(wp + 2 * H_); R3 = *(const f32x4*)(wp + 3 * H_);
        R4 = *(const f32x4*)(wp + 4 * H_); R5 = *(const f32x4*)(wp + 5 * H_);
        R6 = *(const f32x4*)(wp + 6 * H_); R7 = *(const f32x4*)(wp + 7 * H_);
    }

    // ================= decoder: 512 steps; dense piggybacked =================
    // Step t reads buffer holding dec state after step t-1 -> dense -> out[(t-1)*V].
    {
        const int*   ids_d = lds_ids + S_;
        const float* Td    = Tg + V_ * H_;
        int2  idpr = make_int2(0, 0);
        int   id_next = ids_d[1];
        float Tv      = Td[ids_d[0] * H_ + jdiag];
        for (int t = 0; t < S_; t += 2) {
            RNN_STEP(lds_h0, lds_h1, true, true,  ids_d + t, Td,
                     dlane && (t > 0), outd + (t - 1) * V_);
            RNN_STEP(lds_h1, lds_h0, true, false, ids_d + t, Td,
                     dlane, outd + t * V_);
        }
    }

    // epilogue: dense on final state (decoder t=511 wrote lds_h0) -> logits[511]
    {
        const f32x4* hbp = (const f32x4*)(lds_h0 + 12 * kk);
        f32x4 ha = hbp[0], hc = hbp[1];
        float d = dot8(ha, hc, D0, D1);
        d = dpp_add<RR1>(dpp_add<RR2>(dpp_add<RR4>(dpp_add<RR8>(d))));
        if (dlane) outd[(S_ - 1) * V_] = d + db;
    }
}

extern "C" void kernel_launch(void* const* d_in, const int* in_sizes, int n_in,
                              void* d_out, int out_size, void* d_ws, size_t ws_size,
                              hipStream_t stream) {
    const int*   enc_ids = (const int*)d_in[0];
    const int*   dec_ids = (const int*)d_in[1];
    const float* embed   = (const float*)d_in[2];
    const float* enc_Wx  = (const float*)d_in[3];
    const float* enc_Wh  = (const float*)d_in[4];
    const float* enc_b   = (const float*)d_in[5];
    const float* dec_Wx  = (const float*)d_in[6];
    const float* dec_Wh  = (const float*)d_in[7];
    const float* dec_b   = (const float*)d_in[8];
    const float* dense_W = (const float*)d_in[9];
    const float* dense_b = (const float*)d_in[10];
    float* out = (float*)d_out;
    float* Tg  = (float*)d_ws;   // 2*27*128 floats = 27648 B

    hipLaunchKernelGGL(prep_T, dim3(2 * V_), dim3(H_), 0, stream,
                       embed, enc_Wx, enc_b, dec_Wx, dec_b, Tg);
    hipLaunchKernelGGL(seq2seq_rnn_kernel, dim3(256), dim3(512), 0, stream,
                       enc_ids, dec_ids, enc_Wh, dec_Wh, dense_W, dense_b, Tg, out);
}